// Round 2
// baseline (638.138 us; speedup 1.0000x reference)
//
#include <hip/hip_runtime.h>
#include <hip/hip_fp16.h>
#include <math.h>

#define EMB_DIM 256
#define NUM_EMB 2048
#define N_ROWS  65536            // 64*32*32
#define N_ELEM  16777216         // N_ROWS * EMB_DIM
#define EPS_GAP 5e-3f            // ~8.5 sigma of 2-pass ordering error

// ---- workspace layout (in 4-byte elements) ----
#define IDX_OFF    0             // int[65536]
#define XSQ_OFF    65536         // float[65536]
#define ESQ_OFF    131072        // float[2048]  exact ||e||^2 (fallback)
#define ESQH_OFF   133120        // float[2048]  ||eh||^2 (fp16-rounded, main)
#define HIST_OFF   135168        // int[2048]
#define BKT_OFF    137216        // float[256]
#define CNT_OFF    137472        // int[1]
#define FLG_OFF    137473        // int[65536]
#define CBT_OFF    262144        // float[2048][256]  (transposed codebook)
#define CBTH_OFF   786432        // f16 [2048][256] hi plane (1 MB)
// total 1048576 floats = 4 MB of ws

typedef __attribute__((ext_vector_type(8))) _Float16 half8;
typedef __attribute__((ext_vector_type(4))) float f32x4;
typedef unsigned int u32;

__device__ __forceinline__ void gl_lds16(const void* g, void* l) {
    __builtin_amdgcn_global_load_lds(
        (const __attribute__((address_space(1))) u32*)g,
        (__attribute__((address_space(3))) u32*)l, 16, 0, 0);
}

// ---------- prep: exact ||e||^2 (fallback) + ||eh||^2 (main, fp16-rounded) ----------
__global__ __launch_bounds__(256) void esq_k(const float* __restrict__ cb,
                                             float* __restrict__ esq,
                                             float* __restrict__ esqh) {
    int e = blockIdx.x * 256 + threadIdx.x;
    float s0 = 0.f, s1 = 0.f, s2 = 0.f, s3 = 0.f;
    float h0 = 0.f, h1 = 0.f, h2 = 0.f, h3 = 0.f;
    for (int d = 0; d < EMB_DIM; d += 4) {
        float c0 = cb[(d + 0) * NUM_EMB + e];
        float c1 = cb[(d + 1) * NUM_EMB + e];
        float c2 = cb[(d + 2) * NUM_EMB + e];
        float c3 = cb[(d + 3) * NUM_EMB + e];
        s0 = fmaf(c0, c0, s0); s1 = fmaf(c1, c1, s1);
        s2 = fmaf(c2, c2, s2); s3 = fmaf(c3, c3, s3);
        float q0 = __half2float(__float2half(c0));
        float q1 = __half2float(__float2half(c1));
        float q2 = __half2float(__float2half(c2));
        float q3 = __half2float(__float2half(c3));
        h0 = fmaf(q0, q0, h0); h1 = fmaf(q1, q1, h1);
        h2 = fmaf(q2, q2, h2); h3 = fmaf(q3, q3, h3);
    }
    esq[e]  = (s0 + s1) + (s2 + s3);
    esqh[e] = (h0 + h1) + (h2 + h3);
}

// ---------- prep: transpose codebook to [2048][256] fp32 + fp16 hi plane ----------
__global__ __launch_bounds__(256) void prep_cbt(const float* __restrict__ cb,
                                                float* __restrict__ cbT,
                                                __half* __restrict__ cbTh) {
    __shared__ float lt[64][65];
    int t = threadIdx.x;
    int et = (blockIdx.x & 31) * 64;   // e-tile base
    int dt = (blockIdx.x >> 5) * 64;   // d-tile base
    #pragma unroll
    for (int p = 0; p < 4; ++p) {
        int d  = p * 16 + (t >> 4);
        int e4 = (t & 15) * 4;
        const float4 v = *(const float4*)&cb[(dt + d) * NUM_EMB + et + e4];
        lt[d][e4] = v.x; lt[d][e4 + 1] = v.y; lt[d][e4 + 2] = v.z; lt[d][e4 + 3] = v.w;
    }
    __syncthreads();
    #pragma unroll
    for (int p = 0; p < 4; ++p) {
        int e  = p * 16 + (t >> 4);
        int d4 = (t & 15) * 4;
        float a[4] = {lt[d4][e], lt[d4 + 1][e], lt[d4 + 2][e], lt[d4 + 3][e]};
        *(float4*)&cbT[(et + e) * EMB_DIM + dt + d4] = make_float4(a[0], a[1], a[2], a[3]);
        unsigned short hb[4];
        #pragma unroll
        for (int i = 0; i < 4; ++i)
            hb[i] = __half_as_ushort(__float2half(a[i]));
        *(ushort4*)&cbTh[(et + e) * EMB_DIM + dt + d4] = make_ushort4(hb[0], hb[1], hb[2], hb[3]);
    }
}

// ---------- prep: x -> fp16 hi/lo planes + ||x||^2 ----------
__global__ __launch_bounds__(256) void prep_x(const float* __restrict__ x,
                                              __half* __restrict__ xh,
                                              __half* __restrict__ xl,
                                              float* __restrict__ xsq) {
    int t = threadIdx.x;
    int row = blockIdx.x * 4 + (t >> 6);
    int c = (t & 63) * 4;
    const float4 v = *(const float4*)&x[row * EMB_DIM + c];
    float a[4] = {v.x, v.y, v.z, v.w};
    unsigned short hb[4], lb[4];
    float s = 0.f;
    #pragma unroll
    for (int i = 0; i < 4; ++i) {
        __half h = __float2half(a[i]);
        __half l = __float2half(a[i] - __half2float(h));
        hb[i] = __half_as_ushort(h); lb[i] = __half_as_ushort(l);
        s = fmaf(a[i], a[i], s);
    }
    *(ushort4*)&xh[row * EMB_DIM + c] = make_ushort4(hb[0], hb[1], hb[2], hb[3]);
    *(ushort4*)&xl[row * EMB_DIM + c] = make_ushort4(lb[0], lb[1], lb[2], lb[3]);
    #pragma unroll
    for (int o = 32; o > 0; o >>= 1) s += __shfl_down(s, o, 64);
    if ((t & 63) == 0) xsq[row] = s;
}

// ---------- main: 2-pass MFMA score + per-row argmin, double-buffered 2-phase ----------
// 1024 blocks x 256 thr. Block = 64 rows; 8 n-tiles of 256 cols, K=256 in 8 steps.
// score v = ||eh||^2 - 2*(x . eh)  (row-constant ||x||^2 cancels in argmin & gap).
// sim = xh.eh + xl.eh  -> exact x.eh in fp32 accum.
// 2-phase: stage step s+1 into buf^1 BEFORE computing step s from buf; one barrier/step.
#define BUFH 12288   // halfs per LDS buffer: A-hi 2048 + A-lo 2048 + B 8192
__global__ __launch_bounds__(256, 3) void argmin_mfma(
    const __half* __restrict__ xh_, const __half* __restrict__ xl_,
    const __half* __restrict__ cbh_, const float* __restrict__ esqh,
    int* __restrict__ idx_out, int* __restrict__ cnt, int* __restrict__ flg) {

    __shared__ float smemf[12288];                 // 48 KB = 2 x BUFH halfs
    _Float16* lds = (_Float16*)smemf;

    const _Float16* xh  = (const _Float16*)xh_;
    const _Float16* xl  = (const _Float16*)xl_;
    const _Float16* cbh = (const _Float16*)cbh_;

    const int t = threadIdx.x;
    const int w = t >> 6, L = t & 63;
    const int wm = (w >> 1) * 32, wn = (w & 1) * 128;
    const int lm = L & 15, lq = L >> 4;
    const int ph = (lm >> 1) & 3;                  // frag-read XOR swizzle phase
    const int rowbase = blockIdx.x * 64;

    // staging geometry: each gl_lds call stages 16 rows; source chunk XOR-swizzled
    const int srow = L >> 2;                       // row within 16-row group
    const int sq   = (L & 3) ^ ((L >> 3) & 3);     // swizzled source chunk (x8 f16)

    const _Float16* pa_h = xh + (size_t)(rowbase + w * 16 + srow) * EMB_DIM + sq * 8;
    const _Float16* pa_l = xl + (size_t)(rowbase + w * 16 + srow) * EMB_DIM + sq * 8;
    const _Float16* pb0  = cbh + (size_t)(w * 16 + srow) * EMB_DIM + sq * 8;
    // per-wave LDS destination offsets (relative to buffer base)
    const int oAh = (w * 16) * 32;                 // A-hi region at +0
    const int oAl = 2048 + (w * 16) * 32;          // A-lo region at +2048
    const int oB  = 4096 + (w * 16) * 32;          // B region at +4096

    float best[8], b2[8];
    int   bi[8];
    #pragma unroll
    for (int s = 0; s < 8; ++s) { best[s] = 3.4e38f; b2[s] = 3.4e38f; bi[s] = 0; }

    // prologue: stage (nt=0, kt=0) into buf 0
    {
        _Float16* bb = lds;
        gl_lds16(pa_h, bb + oAh);
        gl_lds16(pa_l, bb + oAl);
        gl_lds16(pb0,                 bb + oB);
        gl_lds16(pb0 +  64 * EMB_DIM, bb + oB + 2048);
        gl_lds16(pb0 + 128 * EMB_DIM, bb + oB + 4096);
        gl_lds16(pb0 + 192 * EMB_DIM, bb + oB + 6144);
    }
    __syncthreads();
    int cur = 0;

    for (int nt = 0; nt < 8; ++nt) {
        f32x4 acc[2][8];
        #pragma unroll
        for (int f = 0; f < 2; ++f)
            #pragma unroll
            for (int g = 0; g < 8; ++g)
                acc[f][g] = (f32x4){0.f, 0.f, 0.f, 0.f};

        for (int kt = 0; kt < 8; ++kt) {
            // phase 1: issue next step's stage into the other buffer
            const int step = nt * 8 + kt;
            if (step < 63) {
                const int ns  = step + 1;
                const int nnt = ns >> 3, nkt = ns & 7;
                const int ko  = nkt * 32;
                _Float16* bb = lds + (cur ^ 1) * BUFH;
                const _Float16* pb = pb0 + (size_t)nnt * 256 * EMB_DIM + ko;
                gl_lds16(pa_h + ko, bb + oAh);
                gl_lds16(pa_l + ko, bb + oAl);
                gl_lds16(pb,                 bb + oB);
                gl_lds16(pb +  64 * EMB_DIM, bb + oB + 2048);
                gl_lds16(pb + 128 * EMB_DIM, bb + oB + 4096);
                gl_lds16(pb + 192 * EMB_DIM, bb + oB + 6144);
            }

            // phase 2: compute current step from buf[cur]
            const _Float16* sa_hi = lds + cur * BUFH;
            const _Float16* sa_lo = sa_hi + 2048;
            const _Float16* sb_hi = sa_hi + 4096;

            half8 ah[2], al[2], bh[8];
            #pragma unroll
            for (int f = 0; f < 2; ++f) {
                int off = (wm + f * 16 + lm) * 32 + ((lq ^ ph) * 8);
                ah[f] = *(const half8*)&sa_hi[off];
                al[f] = *(const half8*)&sa_lo[off];
            }
            #pragma unroll
            for (int g = 0; g < 8; ++g) {
                int off = (wn + g * 16 + lm) * 32 + ((lq ^ ph) * 8);
                bh[g] = *(const half8*)&sb_hi[off];
            }
            #pragma unroll
            for (int f = 0; f < 2; ++f)
                #pragma unroll
                for (int g = 0; g < 8; ++g) {
                    acc[f][g] = __builtin_amdgcn_mfma_f32_16x16x32_f16(ah[f], bh[g], acc[f][g], 0, 0, 0);
                    acc[f][g] = __builtin_amdgcn_mfma_f32_16x16x32_f16(al[f], bh[g], acc[f][g], 0, 0, 0);
                }

            // one barrier per step: implicit vmcnt(0) lands after MFMA cover;
            // publishes buf[cur^1] for next step, and closes WAR on buf[cur].
            __syncthreads();
            cur ^= 1;
        }

        // epilogue: v = esqh - 2*sim; running (best, second, index); cols ascend -> strict <
        #pragma unroll
        for (int g = 0; g < 8; ++g) {
            int col = nt * 256 + wn + g * 16 + lm;
            float eq = esqh[col];
            #pragma unroll
            for (int f = 0; f < 2; ++f)
                #pragma unroll
                for (int r = 0; r < 4; ++r) {
                    int s = f * 4 + r;
                    float v = fmaf(-2.0f, acc[f][g][r], eq);
                    float bo = best[s];
                    b2[s]   = fminf(b2[s], fmaxf(bo, v));
                    best[s] = fminf(bo, v);
                    bi[s]   = (v < bo) ? col : bi[s];
                }
        }
    }

    // block-level reduce: 32 candidates per row
    __syncthreads();
    float* rd = smemf;                 // [64][32]
    int*   ri = (int*)(smemf + 2048);
    float* r2 = smemf + 4096;
    #pragma unroll
    for (int f = 0; f < 2; ++f)
        #pragma unroll
        for (int r = 0; r < 4; ++r) {
            int row = wm + f * 16 + lq * 4 + r;
            int c = (w & 1) * 16 + lm;
            rd[row * 32 + c] = best[f * 4 + r];
            ri[row * 32 + c] = bi[f * 4 + r];
            r2[row * 32 + c] = b2[f * 4 + r];
        }
    __syncthreads();
    if (t < 64) {
        int row = t;
        float g1 = rd[row * 32]; int gi = ri[row * 32]; float g2 = r2[row * 32];
        for (int c = 1; c < 32; ++c) {
            float d = rd[row * 32 + c]; int ic = ri[row * 32 + c]; float d2 = r2[row * 32 + c];
            if (d < g1 || (d == g1 && ic < gi)) { g2 = fminf(g1, d2); g1 = d; gi = ic; }
            else g2 = fminf(g2, d);
        }
        idx_out[rowbase + row] = gi;
        if (g2 - g1 < EPS_GAP) {       // near-tie: route to exact fp32 fallback
            int p = atomicAdd(cnt, 1);
            flg[p] = rowbase + row;
        }
    }
}

// ---------- exact fp32 re-check for flagged (near-tie) rows ----------
__global__ __launch_bounds__(256) void fallback_k(const float* __restrict__ x,
                                                  const float* __restrict__ cbT,
                                                  const float* __restrict__ xsq,
                                                  const float* __restrict__ esq,
                                                  const int* __restrict__ cnt,
                                                  const int* __restrict__ rows,
                                                  int* __restrict__ idx) {
    __shared__ float xr[256];
    __shared__ float sd[256];
    __shared__ int   si[256];
    int t = threadIdx.x;
    int n = *cnt;
    for (int fi = blockIdx.x; fi < n; fi += gridDim.x) {
        int row = rows[fi];
        __syncthreads();
        xr[t] = x[row * EMB_DIM + t];
        __syncthreads();
        float bd = 3.4e38f; int bi = 0x7fffffff;
        float xq = xsq[row];
        for (int e = t; e < NUM_EMB; e += 256) {
            const float* cr = &cbT[(size_t)e * EMB_DIM];
            float s0 = 0.f, s1 = 0.f, s2 = 0.f, s3 = 0.f;
            for (int d = 0; d < EMB_DIM; d += 4) {
                s0 = fmaf(xr[d], cr[d], s0);
                s1 = fmaf(xr[d + 1], cr[d + 1], s1);
                s2 = fmaf(xr[d + 2], cr[d + 2], s2);
                s3 = fmaf(xr[d + 3], cr[d + 3], s3);
            }
            float sim = (s0 + s1) + (s2 + s3);
            float dd = (xq + esq[e]) - 2.0f * sim;
            if (dd < bd) { bd = dd; bi = e; }   // e ascends per thread
        }
        sd[t] = bd; si[t] = bi;
        __syncthreads();
        for (int stp = 128; stp > 0; stp >>= 1) {
            if (t < stp) {
                if (sd[t + stp] < sd[t] || (sd[t + stp] == sd[t] && si[t + stp] < si[t])) {
                    sd[t] = sd[t + stp]; si[t] = si[t + stp];
                }
            }
            __syncthreads();
        }
        if (t == 0) idx[row] = si[0];
    }
}

// ---------- quantize + straight-through + loss partials + histogram ----------
// 4 rows/block, float4 loads: wave i owns row 4*blk+i. Same formula (bitwise-identical).
__global__ __launch_bounds__(256) void quant_k(const float* __restrict__ x,
                                               const float* __restrict__ cbT,
                                               const int* __restrict__ idx,
                                               float* __restrict__ out,
                                               float* __restrict__ bkt,
                                               int* __restrict__ hist) {
    int t = threadIdx.x;
    int row = blockIdx.x * 4 + (t >> 6);
    int c = (t & 63) * 4;
    int e = idx[row];
    const float4 q  = *(const float4*)&cbT[(size_t)e * EMB_DIM + c];
    const float4 xv = *(const float4*)&x[(size_t)row * EMB_DIM + c];
    float4 o;
    o.x = xv.x + (q.x - xv.x); o.y = xv.y + (q.y - xv.y);
    o.z = xv.z + (q.z - xv.z); o.w = xv.w + (q.w - xv.w);
    *(float4*)&out[(size_t)row * EMB_DIM + c] = o;
    float dx = xv.x - q.x, dy = xv.y - q.y, dz = xv.z - q.z, dw = xv.w - q.w;
    float val = fmaf(dx, dx, 0.f);
    val = fmaf(dy, dy, val);
    val = fmaf(dz, dz, val);
    val = fmaf(dw, dw, val);
    #pragma unroll
    for (int o2 = 32; o2 > 0; o2 >>= 1) val += __shfl_down(val, o2, 64);
    if ((t & 63) == 0) {
        atomicAdd(&bkt[row & 255], val);
        atomicAdd(&hist[e], 1);
    }
}

// ---------- finalize loss + perplexity ----------
__global__ __launch_bounds__(256) void final_k(const float* __restrict__ bkt,
                                               const int* __restrict__ hist,
                                               float* __restrict__ out) {
    int t = threadIdx.x;
    double ls = (double)bkt[t];
    double ps = 0.0;
    for (int i = t; i < NUM_EMB; i += 256) {
        double p = (double)hist[i] / (double)N_ROWS;
        ps += p * log(p + 1e-10);
    }
    __shared__ double sdd[256], spp[256];
    sdd[t] = ls; spp[t] = ps;
    __syncthreads();
    for (int s = 128; s > 0; s >>= 1) {
        if (t < s) { sdd[t] += sdd[t + s]; spp[t] += spp[t + s]; }
        __syncthreads();
    }
    if (t == 0) {
        out[N_ELEM + 0] = (float)(1.25 * sdd[0] / (double)N_ELEM);
        out[N_ELEM + 1] = (float)exp(-spp[0]);
    }
}

extern "C" void kernel_launch(void* const* d_in, const int* in_sizes, int n_in,
                              void* d_out, int out_size, void* d_ws, size_t ws_size,
                              hipStream_t stream) {
    const float* x  = (const float*)d_in[0];
    const float* cb = (const float*)d_in[1];
    float* out = (float*)d_out;

    float* ws_f = (float*)d_ws;
    int*   ws_i = (int*)d_ws;
    int*   idx  = ws_i + IDX_OFF;
    float* xsq  = ws_f + XSQ_OFF;
    float* esq  = ws_f + ESQ_OFF;
    float* esqh = ws_f + ESQH_OFF;
    int*   hist = ws_i + HIST_OFF;
    float* bkt  = ws_f + BKT_OFF;
    int*   cnt  = ws_i + CNT_OFF;
    int*   flg  = ws_i + FLG_OFF;
    float* cbT  = ws_f + CBT_OFF;
    __half* cbTh = (__half*)(ws_f + CBTH_OFF);

    // x hi/lo fp16 planes live in d_out (overwritten by quant_k at the end)
    __half* xh = (__half*)d_out;
    __half* xl = (__half*)((char*)d_out + 33554432);

    hipMemsetAsync((char*)d_ws + (size_t)HIST_OFF * 4, 0,
                   (NUM_EMB + 256 + 1) * sizeof(float), stream);

    esq_k<<<NUM_EMB / 256, 256, 0, stream>>>(cb, esq, esqh);
    prep_cbt<<<128, 256, 0, stream>>>(cb, cbT, cbTh);
    prep_x<<<N_ROWS / 4, 256, 0, stream>>>(x, xh, xl, xsq);
    argmin_mfma<<<N_ROWS / 64, 256, 0, stream>>>(xh, xl, cbTh, esqh, idx, cnt, flg);
    fallback_k<<<256, 256, 0, stream>>>(x, cbT, xsq, esq, cnt, flg, idx);
    quant_k<<<N_ROWS / 4, 256, 0, stream>>>(x, cbT, idx, out, bkt, hist);
    final_k<<<1, 256, 0, stream>>>(bkt, hist, out);
}

// Round 3
// 562.021 us; speedup vs baseline: 1.1354x; 1.1354x over previous
//
#include <hip/hip_runtime.h>
#include <hip/hip_fp16.h>
#include <math.h>

#define EMB_DIM 256
#define NUM_EMB 2048
#define N_ROWS  65536            // 64*32*32
#define N_ELEM  16777216         // N_ROWS * EMB_DIM
#define EPS_GAP 5e-3f            // ~8.5 sigma of 2-pass ordering error

// ---- workspace layout (in 4-byte elements) ----
#define IDX_OFF    0             // int[65536]
#define XSQ_OFF    65536         // float[65536]
#define ESQ_OFF    131072        // float[2048]  exact ||e||^2 (fallback)
#define ESQH_OFF   133120        // float[2048]  ||eh||^2 (fp16-rounded, main)
#define HIST_OFF   135168        // int[2048]
#define BKT_OFF    137216        // float[256]
#define CNT_OFF    137472        // int[1]
#define FLG_OFF    137473        // int[65536]
#define CBT_OFF    262144        // float[2048][256]  (transposed codebook)
#define CBTH_OFF   786432        // f16 [2048][256] hi plane (1 MB)
// total 1048576 floats = 4 MB of ws

typedef __attribute__((ext_vector_type(8))) _Float16 half8;
typedef __attribute__((ext_vector_type(4))) float f32x4;
typedef unsigned int u32;

__device__ __forceinline__ void gl_lds16(const void* g, void* l) {
    __builtin_amdgcn_global_load_lds(
        (const __attribute__((address_space(1))) u32*)g,
        (__attribute__((address_space(3))) u32*)l, 16, 0, 0);
}

// ---------- prep: exact ||e||^2 (fallback) + ||eh||^2 (main, fp16-rounded) ----------
__global__ __launch_bounds__(256) void esq_k(const float* __restrict__ cb,
                                             float* __restrict__ esq,
                                             float* __restrict__ esqh) {
    int e = blockIdx.x * 256 + threadIdx.x;
    float s0 = 0.f, s1 = 0.f, s2 = 0.f, s3 = 0.f;
    float h0 = 0.f, h1 = 0.f, h2 = 0.f, h3 = 0.f;
    for (int d = 0; d < EMB_DIM; d += 4) {
        float c0 = cb[(d + 0) * NUM_EMB + e];
        float c1 = cb[(d + 1) * NUM_EMB + e];
        float c2 = cb[(d + 2) * NUM_EMB + e];
        float c3 = cb[(d + 3) * NUM_EMB + e];
        s0 = fmaf(c0, c0, s0); s1 = fmaf(c1, c1, s1);
        s2 = fmaf(c2, c2, s2); s3 = fmaf(c3, c3, s3);
        float q0 = __half2float(__float2half(c0));
        float q1 = __half2float(__float2half(c1));
        float q2 = __half2float(__float2half(c2));
        float q3 = __half2float(__float2half(c3));
        h0 = fmaf(q0, q0, h0); h1 = fmaf(q1, q1, h1);
        h2 = fmaf(q2, q2, h2); h3 = fmaf(q3, q3, h3);
    }
    esq[e]  = (s0 + s1) + (s2 + s3);
    esqh[e] = (h0 + h1) + (h2 + h3);
}

// ---------- prep: transpose codebook to [2048][256] fp32 + fp16 hi plane ----------
__global__ __launch_bounds__(256) void prep_cbt(const float* __restrict__ cb,
                                                float* __restrict__ cbT,
                                                __half* __restrict__ cbTh) {
    __shared__ float lt[64][65];
    int t = threadIdx.x;
    int et = (blockIdx.x & 31) * 64;   // e-tile base
    int dt = (blockIdx.x >> 5) * 64;   // d-tile base
    #pragma unroll
    for (int p = 0; p < 4; ++p) {
        int d  = p * 16 + (t >> 4);
        int e4 = (t & 15) * 4;
        const float4 v = *(const float4*)&cb[(dt + d) * NUM_EMB + et + e4];
        lt[d][e4] = v.x; lt[d][e4 + 1] = v.y; lt[d][e4 + 2] = v.z; lt[d][e4 + 3] = v.w;
    }
    __syncthreads();
    #pragma unroll
    for (int p = 0; p < 4; ++p) {
        int e  = p * 16 + (t >> 4);
        int d4 = (t & 15) * 4;
        float a[4] = {lt[d4][e], lt[d4 + 1][e], lt[d4 + 2][e], lt[d4 + 3][e]};
        *(float4*)&cbT[(et + e) * EMB_DIM + dt + d4] = make_float4(a[0], a[1], a[2], a[3]);
        unsigned short hb[4];
        #pragma unroll
        for (int i = 0; i < 4; ++i)
            hb[i] = __half_as_ushort(__float2half(a[i]));
        *(ushort4*)&cbTh[(et + e) * EMB_DIM + dt + d4] = make_ushort4(hb[0], hb[1], hb[2], hb[3]);
    }
}

// ---------- prep: x -> fp16 hi/lo planes + ||x||^2 ----------
__global__ __launch_bounds__(256) void prep_x(const float* __restrict__ x,
                                              __half* __restrict__ xh,
                                              __half* __restrict__ xl,
                                              float* __restrict__ xsq) {
    int t = threadIdx.x;
    int row = blockIdx.x * 4 + (t >> 6);
    int c = (t & 63) * 4;
    const float4 v = *(const float4*)&x[row * EMB_DIM + c];
    float a[4] = {v.x, v.y, v.z, v.w};
    unsigned short hb[4], lb[4];
    float s = 0.f;
    #pragma unroll
    for (int i = 0; i < 4; ++i) {
        __half h = __float2half(a[i]);
        __half l = __float2half(a[i] - __half2float(h));
        hb[i] = __half_as_ushort(h); lb[i] = __half_as_ushort(l);
        s = fmaf(a[i], a[i], s);
    }
    *(ushort4*)&xh[row * EMB_DIM + c] = make_ushort4(hb[0], hb[1], hb[2], hb[3]);
    *(ushort4*)&xl[row * EMB_DIM + c] = make_ushort4(lb[0], lb[1], lb[2], lb[3]);
    #pragma unroll
    for (int o = 32; o > 0; o >>= 1) s += __shfl_down(s, o, 64);
    if ((t & 63) == 0) xsq[row] = s;
}

// ---------- main: 2-pass MFMA score + per-row argmin ----------
// Triple-buffered counted-vmcnt pipeline (T3/T4): per step,
//   sched_barrier(0); s_waitcnt vmcnt(6); s_barrier;
//   STAGE(step+2 -> buf[(step+2)%3]); ds_read buf[step%3]; MFMA (setprio 1).
// Loads stay in flight across barriers (never drained to 0 in main loop).
// Buffers: mod-3 rotation => reads (s%3), in-flight writes ((s+1)%3,(s+2)%3) disjoint.
// score v = ||eh||^2 - 2*(x . eh); sim = xh.eh + xl.eh (exact x.eh in fp32 accum).
#define BUFH 12288   // halfs per LDS buffer: A-hi 2048 + A-lo 2048 + B 8192
__global__ __launch_bounds__(256, 2) void argmin_mfma(
    const __half* __restrict__ xh_, const __half* __restrict__ xl_,
    const __half* __restrict__ cbh_, const float* __restrict__ esqh,
    int* __restrict__ idx_out, int* __restrict__ cnt, int* __restrict__ flg) {

    __shared__ _Float16 ldsbuf[3 * BUFH];          // 72 KB -> 2 blocks/CU
    _Float16* lds = ldsbuf;

    const _Float16* xh  = (const _Float16*)xh_;
    const _Float16* xl  = (const _Float16*)xl_;
    const _Float16* cbh = (const _Float16*)cbh_;

    const int t = threadIdx.x;
    const int w = t >> 6, L = t & 63;
    const int wm = (w >> 1) * 32, wn = (w & 1) * 128;
    const int lm = L & 15, lq = L >> 4;
    const int ph = (lm >> 1) & 3;                  // frag-read XOR swizzle phase
    const int rowbase = blockIdx.x * 64;

    // staging geometry: each gl_lds call stages 16 rows; source chunk XOR-swizzled
    const int srow = L >> 2;                       // row within 16-row group
    const int sq   = (L & 3) ^ ((L >> 3) & 3);     // swizzled source chunk (x8 f16)

    const _Float16* pa_h = xh + (size_t)(rowbase + w * 16 + srow) * EMB_DIM + sq * 8;
    const _Float16* pa_l = xl + (size_t)(rowbase + w * 16 + srow) * EMB_DIM + sq * 8;
    const _Float16* pb0  = cbh + (size_t)(w * 16 + srow) * EMB_DIM + sq * 8;
    // per-wave LDS destination offsets (relative to buffer base)
    const int oAh = (w * 16) * 32;                 // A-hi region at +0
    const int oAl = 2048 + (w * 16) * 32;          // A-lo region at +2048
    const int oB  = 4096 + (w * 16) * 32;          // B region at +4096

    float best[8], b2[8];
    int   bi[8];
    #pragma unroll
    for (int s = 0; s < 8; ++s) { best[s] = 3.4e38f; b2[s] = 3.4e38f; bi[s] = 0; }

    // stage group gs (step index) into buffer bb
    #define STAGE(gs, bb) do {                                              \
        const int nnt_ = (gs) >> 3, nkt_ = (gs) & 7;                        \
        const int ko_  = nkt_ * 32;                                         \
        const _Float16* pb_ = pb0 + (size_t)nnt_ * 256 * EMB_DIM + ko_;     \
        gl_lds16(pa_h + ko_, (bb) + oAh);                                   \
        gl_lds16(pa_l + ko_, (bb) + oAl);                                   \
        gl_lds16(pb_,                 (bb) + oB);                           \
        gl_lds16(pb_ +  64 * EMB_DIM, (bb) + oB + 2048);                    \
        gl_lds16(pb_ + 128 * EMB_DIM, (bb) + oB + 4096);                    \
        gl_lds16(pb_ + 192 * EMB_DIM, (bb) + oB + 6144);                    \
    } while (0)

    // prologue: stage groups 0 and 1 into buffers 0 and 1
    STAGE(0, lds);
    STAGE(1, lds + BUFH);

    for (int nt = 0; nt < 8; ++nt) {
        f32x4 acc[2][8];
        #pragma unroll
        for (int f = 0; f < 2; ++f)
            #pragma unroll
            for (int g = 0; g < 8; ++g)
                acc[f][g] = (f32x4){0.f, 0.f, 0.f, 0.f};

        for (int kt = 0; kt < 8; ++kt) {
            const int step = nt * 8 + kt;

            // pin prior step's ds_reads/MFMAs above the sync point
            __builtin_amdgcn_sched_barrier(0);
            if (step < 63) {
                asm volatile("s_waitcnt vmcnt(6)" ::: "memory");   // group-s retired; s+1,s+2 in flight
            } else {
                asm volatile("s_waitcnt vmcnt(0)" ::: "memory");   // final step: drain
            }
            __builtin_amdgcn_s_barrier();
            __builtin_amdgcn_sched_barrier(0);

            // issue group step+2 into buf[(step+2)%3]
            if (step < 62)
                STAGE(step + 2, lds + ((step + 2) % 3) * BUFH);

            // compute current step from buf[step%3]
            const _Float16* sa_hi = lds + (step % 3) * BUFH;
            const _Float16* sa_lo = sa_hi + 2048;
            const _Float16* sb_hi = sa_hi + 4096;

            half8 ah[2], al[2], bh[8];
            #pragma unroll
            for (int f = 0; f < 2; ++f) {
                int off = (wm + f * 16 + lm) * 32 + ((lq ^ ph) * 8);
                ah[f] = *(const half8*)&sa_hi[off];
                al[f] = *(const half8*)&sa_lo[off];
            }
            #pragma unroll
            for (int g = 0; g < 8; ++g) {
                int off = (wn + g * 16 + lm) * 32 + ((lq ^ ph) * 8);
                bh[g] = *(const half8*)&sb_hi[off];
            }
            __builtin_amdgcn_s_setprio(1);
            #pragma unroll
            for (int f = 0; f < 2; ++f)
                #pragma unroll
                for (int g = 0; g < 8; ++g) {
                    acc[f][g] = __builtin_amdgcn_mfma_f32_16x16x32_f16(ah[f], bh[g], acc[f][g], 0, 0, 0);
                    acc[f][g] = __builtin_amdgcn_mfma_f32_16x16x32_f16(al[f], bh[g], acc[f][g], 0, 0, 0);
                }
            __builtin_amdgcn_s_setprio(0);
        }

        // epilogue: v = esqh - 2*sim; running (best, second, index); cols ascend -> strict <
        #pragma unroll
        for (int g = 0; g < 8; ++g) {
            int col = nt * 256 + wn + g * 16 + lm;
            float eq = esqh[col];
            #pragma unroll
            for (int f = 0; f < 2; ++f)
                #pragma unroll
                for (int r = 0; r < 4; ++r) {
                    int s = f * 4 + r;
                    float v = fmaf(-2.0f, acc[f][g][r], eq);
                    float bo = best[s];
                    b2[s]   = fminf(b2[s], fmaxf(bo, v));
                    best[s] = fminf(bo, v);
                    bi[s]   = (v < bo) ? col : bi[s];
                }
        }
    }
    #undef STAGE

    // block-level reduce: 32 candidates per row
    __syncthreads();
    float* smemf = (float*)ldsbuf;
    float* rd = smemf;                 // [64][32]
    int*   ri = (int*)(smemf + 2048);
    float* r2 = smemf + 4096;
    #pragma unroll
    for (int f = 0; f < 2; ++f)
        #pragma unroll
        for (int r = 0; r < 4; ++r) {
            int row = wm + f * 16 + lq * 4 + r;
            int c = (w & 1) * 16 + lm;
            rd[row * 32 + c] = best[f * 4 + r];
            ri[row * 32 + c] = bi[f * 4 + r];
            r2[row * 32 + c] = b2[f * 4 + r];
        }
    __syncthreads();
    if (t < 64) {
        int row = t;
        float g1 = rd[row * 32]; int gi = ri[row * 32]; float g2 = r2[row * 32];
        for (int c = 1; c < 32; ++c) {
            float d = rd[row * 32 + c]; int ic = ri[row * 32 + c]; float d2 = r2[row * 32 + c];
            if (d < g1 || (d == g1 && ic < gi)) { g2 = fminf(g1, d2); g1 = d; gi = ic; }
            else g2 = fminf(g2, d);
        }
        idx_out[rowbase + row] = gi;
        if (g2 - g1 < EPS_GAP) {       // near-tie: route to exact fp32 fallback
            int p = atomicAdd(cnt, 1);
            flg[p] = rowbase + row;
        }
    }
}

// ---------- exact fp32 re-check for flagged (near-tie) rows ----------
__global__ __launch_bounds__(256) void fallback_k(const float* __restrict__ x,
                                                  const float* __restrict__ cbT,
                                                  const float* __restrict__ xsq,
                                                  const float* __restrict__ esq,
                                                  const int* __restrict__ cnt,
                                                  const int* __restrict__ rows,
                                                  int* __restrict__ idx) {
    __shared__ float xr[256];
    __shared__ float sd[256];
    __shared__ int   si[256];
    int t = threadIdx.x;
    int n = *cnt;
    for (int fi = blockIdx.x; fi < n; fi += gridDim.x) {
        int row = rows[fi];
        __syncthreads();
        xr[t] = x[row * EMB_DIM + t];
        __syncthreads();
        float bd = 3.4e38f; int bi = 0x7fffffff;
        float xq = xsq[row];
        for (int e = t; e < NUM_EMB; e += 256) {
            const float* cr = &cbT[(size_t)e * EMB_DIM];
            float s0 = 0.f, s1 = 0.f, s2 = 0.f, s3 = 0.f;
            for (int d = 0; d < EMB_DIM; d += 4) {
                s0 = fmaf(xr[d], cr[d], s0);
                s1 = fmaf(xr[d + 1], cr[d + 1], s1);
                s2 = fmaf(xr[d + 2], cr[d + 2], s2);
                s3 = fmaf(xr[d + 3], cr[d + 3], s3);
            }
            float sim = (s0 + s1) + (s2 + s3);
            float dd = (xq + esq[e]) - 2.0f * sim;
            if (dd < bd) { bd = dd; bi = e; }   // e ascends per thread
        }
        sd[t] = bd; si[t] = bi;
        __syncthreads();
        for (int stp = 128; stp > 0; stp >>= 1) {
            if (t < stp) {
                if (sd[t + stp] < sd[t] || (sd[t + stp] == sd[t] && si[t + stp] < si[t])) {
                    sd[t] = sd[t + stp]; si[t] = si[t + stp];
                }
            }
            __syncthreads();
        }
        if (t == 0) idx[row] = si[0];
    }
}

// ---------- quantize + straight-through + loss partials + histogram ----------
// 4 rows/block, float4 loads: wave i owns row 4*blk+i. Same formula (bitwise-identical).
__global__ __launch_bounds__(256) void quant_k(const float* __restrict__ x,
                                               const float* __restrict__ cbT,
                                               const int* __restrict__ idx,
                                               float* __restrict__ out,
                                               float* __restrict__ bkt,
                                               int* __restrict__ hist) {
    int t = threadIdx.x;
    int row = blockIdx.x * 4 + (t >> 6);
    int c = (t & 63) * 4;
    int e = idx[row];
    const float4 q  = *(const float4*)&cbT[(size_t)e * EMB_DIM + c];
    const float4 xv = *(const float4*)&x[(size_t)row * EMB_DIM + c];
    float4 o;
    o.x = xv.x + (q.x - xv.x); o.y = xv.y + (q.y - xv.y);
    o.z = xv.z + (q.z - xv.z); o.w = xv.w + (q.w - xv.w);
    *(float4*)&out[(size_t)row * EMB_DIM + c] = o;
    float dx = xv.x - q.x, dy = xv.y - q.y, dz = xv.z - q.z, dw = xv.w - q.w;
    float val = fmaf(dx, dx, 0.f);
    val = fmaf(dy, dy, val);
    val = fmaf(dz, dz, val);
    val = fmaf(dw, dw, val);
    #pragma unroll
    for (int o2 = 32; o2 > 0; o2 >>= 1) val += __shfl_down(val, o2, 64);
    if ((t & 63) == 0) {
        atomicAdd(&bkt[row & 255], val);
        atomicAdd(&hist[e], 1);
    }
}

// ---------- finalize loss + perplexity ----------
__global__ __launch_bounds__(256) void final_k(const float* __restrict__ bkt,
                                               const int* __restrict__ hist,
                                               float* __restrict__ out) {
    int t = threadIdx.x;
    double ls = (double)bkt[t];
    double ps = 0.0;
    for (int i = t; i < NUM_EMB; i += 256) {
        double p = (double)hist[i] / (double)N_ROWS;
        ps += p * log(p + 1e-10);
    }
    __shared__ double sdd[256], spp[256];
    sdd[t] = ls; spp[t] = ps;
    __syncthreads();
    for (int s = 128; s > 0; s >>= 1) {
        if (t < s) { sdd[t] += sdd[t + s]; spp[t] += spp[t + s]; }
        __syncthreads();
    }
    if (t == 0) {
        out[N_ELEM + 0] = (float)(1.25 * sdd[0] / (double)N_ELEM);
        out[N_ELEM + 1] = (float)exp(-spp[0]);
    }
}

extern "C" void kernel_launch(void* const* d_in, const int* in_sizes, int n_in,
                              void* d_out, int out_size, void* d_ws, size_t ws_size,
                              hipStream_t stream) {
    const float* x  = (const float*)d_in[0];
    const float* cb = (const float*)d_in[1];
    float* out = (float*)d_out;

    float* ws_f = (float*)d_ws;
    int*   ws_i = (int*)d_ws;
    int*   idx  = ws_i + IDX_OFF;
    float* xsq  = ws_f + XSQ_OFF;
    float* esq  = ws_f + ESQ_OFF;
    float* esqh = ws_f + ESQH_OFF;
    int*   hist = ws_i + HIST_OFF;
    float* bkt  = ws_f + BKT_OFF;
    int*   cnt  = ws_i + CNT_OFF;
    int*   flg  = ws_i + FLG_OFF;
    float* cbT  = ws_f + CBT_OFF;
    __half* cbTh = (__half*)(ws_f + CBTH_OFF);

    // x hi/lo fp16 planes live in d_out (overwritten by quant_k at the end)
    __half* xh = (__half*)d_out;
    __half* xl = (__half*)((char*)d_out + 33554432);

    hipMemsetAsync((char*)d_ws + (size_t)HIST_OFF * 4, 0,
                   (NUM_EMB + 256 + 1) * sizeof(float), stream);

    esq_k<<<NUM_EMB / 256, 256, 0, stream>>>(cb, esq, esqh);
    prep_cbt<<<128, 256, 0, stream>>>(cb, cbT, cbTh);
    prep_x<<<N_ROWS / 4, 256, 0, stream>>>(x, xh, xl, xsq);
    argmin_mfma<<<N_ROWS / 64, 256, 0, stream>>>(xh, xl, cbTh, esqh, idx, cnt, flg);
    fallback_k<<<256, 256, 0, stream>>>(x, cbT, xsq, esq, cnt, flg, idx);
    quant_k<<<N_ROWS / 4, 256, 0, stream>>>(x, cbT, idx, out, bkt, hist);
    final_k<<<1, 256, 0, stream>>>(bkt, hist, out);
}

// Round 4
// 500.997 us; speedup vs baseline: 1.2737x; 1.1218x over previous
//
#include <hip/hip_runtime.h>
#include <hip/hip_fp16.h>
#include <math.h>

#define EMB_DIM 256
#define NUM_EMB 2048
#define N_ROWS  65536            // 64*32*32
#define N_ELEM  16777216         // N_ROWS * EMB_DIM
#define EPS_GAP 5e-3f            // ~6.5 sigma of 2-pass ordering error

// ---- workspace layout (in 4-byte elements) ----
#define IDX_OFF    0             // int[65536]
#define XSQ_OFF    65536         // float[65536]
#define ESQ_OFF    131072        // float[2048]  exact ||e||^2 (fallback)
#define ESQH_OFF   133120        // float[2048]  ||eh||^2 (fp16-rounded, main)
#define HIST_OFF   135168        // int[2048]
#define BKT_OFF    137216        // float[256]
#define CNT_OFF    137472        // int[1]
#define FLG_OFF    137473        // int[65536]
#define CBT_OFF    262144        // float[2048][256]  (transposed codebook)
#define CBTH_OFF   786432        // f16 [2048][256] hi plane (1 MB)
// total 1048576 floats = 4 MB of ws

typedef __attribute__((ext_vector_type(8))) _Float16 half8;
typedef __attribute__((ext_vector_type(4))) float f32x4;
typedef unsigned int u32;

__device__ __forceinline__ void gl_lds16(const void* g, void* l) {
    __builtin_amdgcn_global_load_lds(
        (const __attribute__((address_space(1))) u32*)g,
        (__attribute__((address_space(3))) u32*)l, 16, 0, 0);
}

// ---------- prep: exact ||e||^2 (fallback) + ||eh||^2 (main, fp16-rounded) ----------
__global__ __launch_bounds__(256) void esq_k(const float* __restrict__ cb,
                                             float* __restrict__ esq,
                                             float* __restrict__ esqh) {
    int e = blockIdx.x * 256 + threadIdx.x;
    float s0 = 0.f, s1 = 0.f, s2 = 0.f, s3 = 0.f;
    float h0 = 0.f, h1 = 0.f, h2 = 0.f, h3 = 0.f;
    for (int d = 0; d < EMB_DIM; d += 4) {
        float c0 = cb[(d + 0) * NUM_EMB + e];
        float c1 = cb[(d + 1) * NUM_EMB + e];
        float c2 = cb[(d + 2) * NUM_EMB + e];
        float c3 = cb[(d + 3) * NUM_EMB + e];
        s0 = fmaf(c0, c0, s0); s1 = fmaf(c1, c1, s1);
        s2 = fmaf(c2, c2, s2); s3 = fmaf(c3, c3, s3);
        float q0 = __half2float(__float2half(c0));
        float q1 = __half2float(__float2half(c1));
        float q2 = __half2float(__float2half(c2));
        float q3 = __half2float(__float2half(c3));
        h0 = fmaf(q0, q0, h0); h1 = fmaf(q1, q1, h1);
        h2 = fmaf(q2, q2, h2); h3 = fmaf(q3, q3, h3);
    }
    esq[e]  = (s0 + s1) + (s2 + s3);
    esqh[e] = (h0 + h1) + (h2 + h3);
}

// ---------- prep: transpose codebook to [2048][256] fp32 + fp16 hi plane ----------
__global__ __launch_bounds__(256) void prep_cbt(const float* __restrict__ cb,
                                                float* __restrict__ cbT,
                                                __half* __restrict__ cbTh) {
    __shared__ float lt[64][65];
    int t = threadIdx.x;
    int et = (blockIdx.x & 31) * 64;   // e-tile base
    int dt = (blockIdx.x >> 5) * 64;   // d-tile base
    #pragma unroll
    for (int p = 0; p < 4; ++p) {
        int d  = p * 16 + (t >> 4);
        int e4 = (t & 15) * 4;
        const float4 v = *(const float4*)&cb[(dt + d) * NUM_EMB + et + e4];
        lt[d][e4] = v.x; lt[d][e4 + 1] = v.y; lt[d][e4 + 2] = v.z; lt[d][e4 + 3] = v.w;
    }
    __syncthreads();
    #pragma unroll
    for (int p = 0; p < 4; ++p) {
        int e  = p * 16 + (t >> 4);
        int d4 = (t & 15) * 4;
        float a[4] = {lt[d4][e], lt[d4 + 1][e], lt[d4 + 2][e], lt[d4 + 3][e]};
        *(float4*)&cbT[(et + e) * EMB_DIM + dt + d4] = make_float4(a[0], a[1], a[2], a[3]);
        unsigned short hb[4];
        #pragma unroll
        for (int i = 0; i < 4; ++i)
            hb[i] = __half_as_ushort(__float2half(a[i]));
        *(ushort4*)&cbTh[(et + e) * EMB_DIM + dt + d4] = make_ushort4(hb[0], hb[1], hb[2], hb[3]);
    }
}

// ---------- prep: x -> fp16 hi/lo planes + ||x||^2 ----------
__global__ __launch_bounds__(256) void prep_x(const float* __restrict__ x,
                                              __half* __restrict__ xh,
                                              __half* __restrict__ xl,
                                              float* __restrict__ xsq) {
    int t = threadIdx.x;
    int row = blockIdx.x * 4 + (t >> 6);
    int c = (t & 63) * 4;
    const float4 v = *(const float4*)&x[row * EMB_DIM + c];
    float a[4] = {v.x, v.y, v.z, v.w};
    unsigned short hb[4], lb[4];
    float s = 0.f;
    #pragma unroll
    for (int i = 0; i < 4; ++i) {
        __half h = __float2half(a[i]);
        __half l = __float2half(a[i] - __half2float(h));
        hb[i] = __half_as_ushort(h); lb[i] = __half_as_ushort(l);
        s = fmaf(a[i], a[i], s);
    }
    *(ushort4*)&xh[row * EMB_DIM + c] = make_ushort4(hb[0], hb[1], hb[2], hb[3]);
    *(ushort4*)&xl[row * EMB_DIM + c] = make_ushort4(lb[0], lb[1], lb[2], lb[3]);
    #pragma unroll
    for (int o = 32; o > 0; o >>= 1) s += __shfl_down(s, o, 64);
    if ((t & 63) == 0) xsq[row] = s;
}

// ---------- main: 2-pass MFMA score + per-row argmin ----------
// Triple-buffered counted-vmcnt pipeline (T3/T4): per step,
//   sched_barrier(0); s_waitcnt vmcnt(6); s_barrier;
//   STAGE(step+2 -> buf[(step+2)%3]); ds_read buf[step%3]; MFMA (setprio 1).
// Loads stay in flight across barriers (never drained to 0 in main loop).
// score v = ||eh||^2 - 2*(x . eh); sim = xh.eh + xl.eh (exact x.eh in fp32 accum).
#define BUFH 12288   // halfs per LDS buffer: A-hi 2048 + A-lo 2048 + B 8192
__global__ __launch_bounds__(256, 2) void argmin_mfma(
    const __half* __restrict__ xh_, const __half* __restrict__ xl_,
    const __half* __restrict__ cbh_, const float* __restrict__ esqh,
    int* __restrict__ idx_out, int* __restrict__ cnt, int* __restrict__ flg) {

    __shared__ _Float16 ldsbuf[3 * BUFH];          // 72 KB -> 2 blocks/CU
    _Float16* lds = ldsbuf;

    const _Float16* xh  = (const _Float16*)xh_;
    const _Float16* xl  = (const _Float16*)xl_;
    const _Float16* cbh = (const _Float16*)cbh_;

    const int t = threadIdx.x;
    const int w = t >> 6, L = t & 63;
    const int wm = (w >> 1) * 32, wn = (w & 1) * 128;
    const int lm = L & 15, lq = L >> 4;
    const int ph = (lm >> 1) & 3;                  // frag-read XOR swizzle phase
    const int rowbase = blockIdx.x * 64;

    // staging geometry: each gl_lds call stages 16 rows; source chunk XOR-swizzled
    const int srow = L >> 2;                       // row within 16-row group
    const int sq   = (L & 3) ^ ((L >> 3) & 3);     // swizzled source chunk (x8 f16)

    const _Float16* pa_h = xh + (size_t)(rowbase + w * 16 + srow) * EMB_DIM + sq * 8;
    const _Float16* pa_l = xl + (size_t)(rowbase + w * 16 + srow) * EMB_DIM + sq * 8;
    const _Float16* pb0  = cbh + (size_t)(w * 16 + srow) * EMB_DIM + sq * 8;
    // per-wave LDS destination offsets (relative to buffer base)
    const int oAh = (w * 16) * 32;                 // A-hi region at +0
    const int oAl = 2048 + (w * 16) * 32;          // A-lo region at +2048
    const int oB  = 4096 + (w * 16) * 32;          // B region at +4096

    float best[8], b2[8];
    int   bi[8];
    #pragma unroll
    for (int s = 0; s < 8; ++s) { best[s] = 3.4e38f; b2[s] = 3.4e38f; bi[s] = 0; }

    // stage group gs (step index) into buffer bb
    #define STAGE(gs, bb) do {                                              \
        const int nnt_ = (gs) >> 3, nkt_ = (gs) & 7;                        \
        const int ko_  = nkt_ * 32;                                         \
        const _Float16* pb_ = pb0 + (size_t)nnt_ * 256 * EMB_DIM + ko_;     \
        gl_lds16(pa_h + ko_, (bb) + oAh);                                   \
        gl_lds16(pa_l + ko_, (bb) + oAl);                                   \
        gl_lds16(pb_,                 (bb) + oB);                           \
        gl_lds16(pb_ +  64 * EMB_DIM, (bb) + oB + 2048);                    \
        gl_lds16(pb_ + 128 * EMB_DIM, (bb) + oB + 4096);                    \
        gl_lds16(pb_ + 192 * EMB_DIM, (bb) + oB + 6144);                    \
    } while (0)

    // prologue: stage groups 0 and 1 into buffers 0 and 1
    STAGE(0, lds);
    STAGE(1, lds + BUFH);

    for (int nt = 0; nt < 8; ++nt) {
        f32x4 acc[2][8];
        #pragma unroll
        for (int f = 0; f < 2; ++f)
            #pragma unroll
            for (int g = 0; g < 8; ++g)
                acc[f][g] = (f32x4){0.f, 0.f, 0.f, 0.f};

        for (int kt = 0; kt < 8; ++kt) {
            const int step = nt * 8 + kt;

            // pin prior step's ds_reads/MFMAs above the sync point
            __builtin_amdgcn_sched_barrier(0);
            if (step < 63) {
                asm volatile("s_waitcnt vmcnt(6)" ::: "memory");   // group-s retired; s+1,s+2 in flight
            } else {
                asm volatile("s_waitcnt vmcnt(0)" ::: "memory");   // final step: drain
            }
            __builtin_amdgcn_s_barrier();
            __builtin_amdgcn_sched_barrier(0);

            // issue group step+2 into buf[(step+2)%3]
            if (step < 62)
                STAGE(step + 2, lds + ((step + 2) % 3) * BUFH);

            // compute current step from buf[step%3]
            const _Float16* sa_hi = lds + (step % 3) * BUFH;
            const _Float16* sa_lo = sa_hi + 2048;
            const _Float16* sb_hi = sa_hi + 4096;

            half8 ah[2], al[2], bh[8];
            #pragma unroll
            for (int f = 0; f < 2; ++f) {
                int off = (wm + f * 16 + lm) * 32 + ((lq ^ ph) * 8);
                ah[f] = *(const half8*)&sa_hi[off];
                al[f] = *(const half8*)&sa_lo[off];
            }
            #pragma unroll
            for (int g = 0; g < 8; ++g) {
                int off = (wn + g * 16 + lm) * 32 + ((lq ^ ph) * 8);
                bh[g] = *(const half8*)&sb_hi[off];
            }
            __builtin_amdgcn_s_setprio(1);
            #pragma unroll
            for (int f = 0; f < 2; ++f)
                #pragma unroll
                for (int g = 0; g < 8; ++g) {
                    acc[f][g] = __builtin_amdgcn_mfma_f32_16x16x32_f16(ah[f], bh[g], acc[f][g], 0, 0, 0);
                    acc[f][g] = __builtin_amdgcn_mfma_f32_16x16x32_f16(al[f], bh[g], acc[f][g], 0, 0, 0);
                }
            __builtin_amdgcn_s_setprio(0);
        }

        // epilogue: v = esqh - 2*sim; running (best, second, index); cols ascend -> strict <
        #pragma unroll
        for (int g = 0; g < 8; ++g) {
            int col = nt * 256 + wn + g * 16 + lm;
            float eq = esqh[col];
            #pragma unroll
            for (int f = 0; f < 2; ++f)
                #pragma unroll
                for (int r = 0; r < 4; ++r) {
                    int s = f * 4 + r;
                    float v = fmaf(-2.0f, acc[f][g][r], eq);
                    float bo = best[s];
                    b2[s]   = fminf(b2[s], fmaxf(bo, v));
                    best[s] = fminf(bo, v);
                    bi[s]   = (v < bo) ? col : bi[s];
                }
        }
    }
    #undef STAGE

    // block-level reduce: 32 candidates per row
    __syncthreads();
    float* smemf = (float*)ldsbuf;
    float* rd = smemf;                 // [64][32]
    int*   ri = (int*)(smemf + 2048);
    float* r2 = smemf + 4096;
    #pragma unroll
    for (int f = 0; f < 2; ++f)
        #pragma unroll
        for (int r = 0; r < 4; ++r) {
            int row = wm + f * 16 + lq * 4 + r;
            int c = (w & 1) * 16 + lm;
            rd[row * 32 + c] = best[f * 4 + r];
            ri[row * 32 + c] = bi[f * 4 + r];
            r2[row * 32 + c] = b2[f * 4 + r];
        }
    __syncthreads();
    if (t < 64) {
        int row = t;
        float g1 = rd[row * 32]; int gi = ri[row * 32]; float g2 = r2[row * 32];
        for (int c = 1; c < 32; ++c) {
            float d = rd[row * 32 + c]; int ic = ri[row * 32 + c]; float d2 = r2[row * 32 + c];
            if (d < g1 || (d == g1 && ic < gi)) { g2 = fminf(g1, d2); g1 = d; gi = ic; }
            else g2 = fminf(g2, d);
        }
        idx_out[rowbase + row] = gi;
        if (g2 - g1 < EPS_GAP) {       // near-tie: route to exact fp32 fallback
            int p = atomicAdd(cnt, 1);
            flg[p] = rowbase + row;
        }
    }
}

// ---------- exact fp32 re-check for flagged (near-tie) rows ----------
// Coalesced + 4-row batched: cb original [256][2048] layout, lane t owns codes
// {t, 256+t, ...} (same set & visit order as before); per-thread accumulation
// replicates the old 4-partial-sum structure -> bitwise-identical candidates.
__global__ __launch_bounds__(256) void fallback_k(const float* __restrict__ x,
                                                  const float* __restrict__ cb,
                                                  const float* __restrict__ xsq,
                                                  const float* __restrict__ esq,
                                                  const int* __restrict__ cnt,
                                                  const int* __restrict__ rows,
                                                  int* __restrict__ idx) {
    __shared__ float xr[4][256];
    __shared__ float sd[4][256];
    __shared__ int   si[4][256];
    int t = threadIdx.x;
    int n = *cnt;
    for (int base = blockIdx.x * 4; base < n; base += gridDim.x * 4) {
        int rws[4];
        #pragma unroll
        for (int r = 0; r < 4; ++r) {
            int fi = base + r;
            rws[r] = rows[(fi < n) ? fi : (n - 1)];   // pad by repeating last (benign)
        }
        __syncthreads();   // WAR vs previous group's reduce
        #pragma unroll
        for (int r = 0; r < 4; ++r) xr[r][t] = x[(size_t)rws[r] * EMB_DIM + t];
        __syncthreads();

        float bd[4]; int bidx[4];
        #pragma unroll
        for (int r = 0; r < 4; ++r) { bd[r] = 3.4e38f; bidx[r] = 0x7fffffff; }

        for (int j = 0; j < 8; ++j) {
            int e = j * 256 + t;
            float s0[4], s1[4], s2[4], s3[4];
            #pragma unroll
            for (int r = 0; r < 4; ++r) { s0[r] = 0.f; s1[r] = 0.f; s2[r] = 0.f; s3[r] = 0.f; }
            for (int d = 0; d < EMB_DIM; d += 4) {
                float c0 = cb[(size_t)(d + 0) * NUM_EMB + e];
                float c1 = cb[(size_t)(d + 1) * NUM_EMB + e];
                float c2 = cb[(size_t)(d + 2) * NUM_EMB + e];
                float c3 = cb[(size_t)(d + 3) * NUM_EMB + e];
                #pragma unroll
                for (int r = 0; r < 4; ++r) {
                    const float4 xv = *(const float4*)&xr[r][d];
                    s0[r] = fmaf(xv.x, c0, s0[r]);
                    s1[r] = fmaf(xv.y, c1, s1[r]);
                    s2[r] = fmaf(xv.z, c2, s2[r]);
                    s3[r] = fmaf(xv.w, c3, s3[r]);
                }
            }
            float eq = esq[e];
            #pragma unroll
            for (int r = 0; r < 4; ++r) {
                float sim = (s0[r] + s1[r]) + (s2[r] + s3[r]);
                float dd = (xsq[rws[r]] + eq) - 2.0f * sim;
                if (dd < bd[r]) { bd[r] = dd; bidx[r] = e; }   // e ascends per thread
            }
        }
        #pragma unroll
        for (int r = 0; r < 4; ++r) { sd[r][t] = bd[r]; si[r][t] = bidx[r]; }
        __syncthreads();
        for (int r = 0; r < 4; ++r) {
            for (int stp = 128; stp > 0; stp >>= 1) {
                if (t < stp) {
                    if (sd[r][t + stp] < sd[r][t] ||
                        (sd[r][t + stp] == sd[r][t] && si[r][t + stp] < si[r][t])) {
                        sd[r][t] = sd[r][t + stp]; si[r][t] = si[r][t + stp];
                    }
                }
                __syncthreads();
            }
        }
        if (t == 0) {
            #pragma unroll
            for (int r = 0; r < 4; ++r) idx[rws[r]] = si[r][0];
        }
    }
}

// ---------- quantize + straight-through + loss partials + histogram ----------
// 4 rows/block, float4 loads: wave i owns row 4*blk+i. Same formula (bitwise-identical).
__global__ __launch_bounds__(256) void quant_k(const float* __restrict__ x,
                                               const float* __restrict__ cbT,
                                               const int* __restrict__ idx,
                                               float* __restrict__ out,
                                               float* __restrict__ bkt,
                                               int* __restrict__ hist) {
    int t = threadIdx.x;
    int row = blockIdx.x * 4 + (t >> 6);
    int c = (t & 63) * 4;
    int e = idx[row];
    const float4 q  = *(const float4*)&cbT[(size_t)e * EMB_DIM + c];
    const float4 xv = *(const float4*)&x[(size_t)row * EMB_DIM + c];
    float4 o;
    o.x = xv.x + (q.x - xv.x); o.y = xv.y + (q.y - xv.y);
    o.z = xv.z + (q.z - xv.z); o.w = xv.w + (q.w - xv.w);
    *(float4*)&out[(size_t)row * EMB_DIM + c] = o;
    float dx = xv.x - q.x, dy = xv.y - q.y, dz = xv.z - q.z, dw = xv.w - q.w;
    float val = fmaf(dx, dx, 0.f);
    val = fmaf(dy, dy, val);
    val = fmaf(dz, dz, val);
    val = fmaf(dw, dw, val);
    #pragma unroll
    for (int o2 = 32; o2 > 0; o2 >>= 1) val += __shfl_down(val, o2, 64);
    if ((t & 63) == 0) {
        atomicAdd(&bkt[row & 255], val);
        atomicAdd(&hist[e], 1);
    }
}

// ---------- finalize loss + perplexity ----------
__global__ __launch_bounds__(256) void final_k(const float* __restrict__ bkt,
                                               const int* __restrict__ hist,
                                               float* __restrict__ out) {
    int t = threadIdx.x;
    double ls = (double)bkt[t];
    double ps = 0.0;
    for (int i = t; i < NUM_EMB; i += 256) {
        double p = (double)hist[i] / (double)N_ROWS;
        ps += p * log(p + 1e-10);
    }
    __shared__ double sdd[256], spp[256];
    sdd[t] = ls; spp[t] = ps;
    __syncthreads();
    for (int s = 128; s > 0; s >>= 1) {
        if (t < s) { sdd[t] += sdd[t + s]; spp[t] += spp[t + s]; }
        __syncthreads();
    }
    if (t == 0) {
        out[N_ELEM + 0] = (float)(1.25 * sdd[0] / (double)N_ELEM);
        out[N_ELEM + 1] = (float)exp(-spp[0]);
    }
}

extern "C" void kernel_launch(void* const* d_in, const int* in_sizes, int n_in,
                              void* d_out, int out_size, void* d_ws, size_t ws_size,
                              hipStream_t stream) {
    const float* x  = (const float*)d_in[0];
    const float* cb = (const float*)d_in[1];
    float* out = (float*)d_out;

    float* ws_f = (float*)d_ws;
    int*   ws_i = (int*)d_ws;
    int*   idx  = ws_i + IDX_OFF;
    float* xsq  = ws_f + XSQ_OFF;
    float* esq  = ws_f + ESQ_OFF;
    float* esqh = ws_f + ESQH_OFF;
    int*   hist = ws_i + HIST_OFF;
    float* bkt  = ws_f + BKT_OFF;
    int*   cnt  = ws_i + CNT_OFF;
    int*   flg  = ws_i + FLG_OFF;
    float* cbT  = ws_f + CBT_OFF;
    __half* cbTh = (__half*)(ws_f + CBTH_OFF);

    // x hi/lo fp16 planes live in d_out (overwritten by quant_k at the end)
    __half* xh = (__half*)d_out;
    __half* xl = (__half*)((char*)d_out + 33554432);

    hipMemsetAsync((char*)d_ws + (size_t)HIST_OFF * 4, 0,
                   (NUM_EMB + 256 + 1) * sizeof(float), stream);

    esq_k<<<NUM_EMB / 256, 256, 0, stream>>>(cb, esq, esqh);
    prep_cbt<<<128, 256, 0, stream>>>(cb, cbT, cbTh);
    prep_x<<<N_ROWS / 4, 256, 0, stream>>>(x, xh, xl, xsq);
    argmin_mfma<<<N_ROWS / 64, 256, 0, stream>>>(xh, xl, cbTh, esqh, idx, cnt, flg);
    fallback_k<<<512, 256, 0, stream>>>(x, cb, xsq, esq, cnt, flg, idx);
    quant_k<<<N_ROWS / 4, 256, 0, stream>>>(x, cbT, idx, out, bkt, hist);
    final_k<<<1, 256, 0, stream>>>(bkt, hist, out);
}